// Round 8
// baseline (1198.968 us; speedup 1.0000x reference)
//
#include <hip/hip_runtime.h>

// Problem constants (from reference)
#define B_      128
#define NPIX    32      // N = M = 32
#define NNEO    30      // N-2
#define CSTATE  19      // state channels
#define OUTD    21      // OUT_DIM
#define ITERS   10
#define THRESHV 0.0007f

#define STATE_ELEMS (B_ * NPIX * NPIX * CSTATE)   // 2,490,368 floats per buffer
#define NCELLS      (B_ * NNEO * NNEO)            // 115,200
#define CLASS_ELEMS (NCELLS * 3)                  // 345,600
#define HSTRIDE 31    // s_h cell stride: gcd(31,32)=1 -> conflict-free

// ---------------------------------------------------------------------------
// init: zero ONLY the borders of both state buffers (interiors are fully
// written by each step before being read). perc needs no init: step t=0
// derives (px,py)=(i,j) itself.
// ---------------------------------------------------------------------------
__global__ void nca_init(float* __restrict__ stateA, float* __restrict__ stateB) {
    int idx = blockIdx.x * blockDim.x + threadIdx.x;
    const int total = B_ * 124 * CSTATE;
    if (idx >= total) return;
    int c  = idx % CSTATE;
    int t2 = idx / CSTATE;
    int cell = t2 % 124;
    int b    = t2 / 124;
    int i, j;
    if (cell < 32)      { i = 0;  j = cell; }
    else if (cell < 64) { i = 31; j = cell - 32; }
    else { int k = cell - 64; i = 1 + (k >> 1); j = (k & 1) ? 31 : 0; }
    size_t off = (((size_t)b * NPIX + i) * NPIX + j) * CSTATE + c;
    stateA[off] = 0.0f;
    stateB[off] = 0.0f;
}

// ---------------------------------------------------------------------------
// One NCA step. Block = (batch b, row-group rg): row groups {8,8,7,7}, 30
// cols, 1024 threads = 4 "quarters" of 4 waves. Quarter qh computes output
// slice [QOFF(qh), QOFF(qh)+8) of layers 1-2 and [5*qh, 5*qh+6) of layer 3.
// 8 waves/SIMD (32 waves/CU = HW cap).
// CODEGEN RULES (R3-R7 lessons):
//  - ROW-MAJOR s_state + float4 staging ONLY (channel-major variant broke
//    post-timing validation with zero perf gain — do not reintroduce).
//  - Weight loops: rolled or unroll-2 MAX. Full unroll = scratch-spill
//    catastrophe (R6 bench: VGPR 16/32, WRITE_SIZE 119MB/step).
//  - unroll 2 pairs two independent s_load rows per drain (this round's
//    experiment; revert to rolled if VGPR collapses).
// ---------------------------------------------------------------------------
template<bool FIRST, bool LAST>
__global__ __launch_bounds__(1024, 8)
void nca_step(const float* __restrict__ img,
              const float* __restrict__ W1, const float* __restrict__ b1,
              const float* __restrict__ W2, const float* __restrict__ b2,
              const float* __restrict__ W3, const float* __restrict__ b3,
              const float* __restrict__ state_old, float* __restrict__ state_new,
              int* perc, float* __restrict__ guesses_out,
              float* __restrict__ class_out) {
    __shared__ float s_state[10 * NPIX * CSTATE];   // 6080 floats = 24.3 KB
    __shared__ float s_img[NPIX * NPIX];            // 1024 floats = 4 KB
    __shared__ float s_h[240 * HSTRIDE];            // 7440 floats = 29.8 KB

    const int b   = blockIdx.y;
    const int rg  = blockIdx.x;
    const int i0  = (rg < 2) ? rg * 8 : 16 + (rg - 2) * 7;
    const int nr  = (rg < 2) ? 8 : 7;
    const int tid = threadIdx.x;
    const int qh  = __builtin_amdgcn_readfirstlane(tid >> 8);   // wave-uniform
    const int cell = tid & 255;
    const int qoff = (qh == 0) ? 0 : (qh == 1) ? 8 : (qh == 2) ? 14 : 22;
    const int off3 = 5 * qh;

    // --- stage state rows [i0, i0+nr+2) and the full image into LDS ---
    if (!FIRST) {
        const int n4 = (nr + 2) * NPIX * CSTATE / 4;   // divisible by 4
        const float4* gstate4 =
            (const float4*)(state_old + ((size_t)b * NPIX + i0) * NPIX * CSTATE);
        float4* s_state4 = (float4*)s_state;
        for (int t = tid; t < n4; t += 1024) s_state4[t] = gstate4[t];
    }
    if (tid < NPIX * NPIX / 4) {
        ((float4*)s_img)[tid] = ((const float4*)(img + (size_t)b * NPIX * NPIX))[tid];
    }
    __syncthreads();

    const int cells = nr * NNEO;
    const bool active = cell < cells;

    int r = 0, j = 0, i = 0, gcell = 0, px = 0, py = 0;
    if (active) {
        r = cell / NNEO;
        j = cell % NNEO;
        i = i0 + r;
        gcell = (b * NNEO + i) * NNEO + j;
        if (FIRST) { px = i; py = j; }
        else       { px = perc[2 * gcell]; py = perc[2 * gcell + 1]; }
    }

    // ---------------- layer 1: 182 -> 30 (this thread: 8 @ qoff) ----------
    float h1[8];
    {
        const float* __restrict__ bb = b1 + qoff;
#pragma unroll
        for (int q = 0; q < 8; q++) h1[q] = bb[q];
    }
    if (active) {
        for (int pr = 0; pr < 3; pr++) {
            for (int pc = 0; pc < 3; pc++) {
                const int p9 = pr * 3 + pc;
                const float iv = s_img[(px + pr) * NPIX + (py + pc)];
                {
                    const float* __restrict__ wr = W1 + (p9 * 20) * 30 + qoff;
#pragma unroll
                    for (int q = 0; q < 8; q++) h1[q] += iv * wr[q];
                }
                if (!FIRST) {
                    const int sbase = ((r + pr) * NPIX + (j + pc)) * CSTATE;
                    float fv[CSTATE];
#pragma unroll
                    for (int ch = 0; ch < CSTATE; ch++) fv[ch] = s_state[sbase + ch];
#pragma unroll 2
                    for (int ch = 0; ch < CSTATE; ch++) {
                        const float* __restrict__ wr =
                            W1 + (p9 * 20 + 1 + ch) * 30 + qoff;
#pragma unroll
                        for (int q = 0; q < 8; q++) h1[q] += fv[ch] * wr[q];
                    }
                }
            }
        }
        const float posx = (float)(px - 16) * (1.0f / 16.0f);
        const float posy = (float)(py - 16) * (1.0f / 16.0f);
        const float* __restrict__ wx = W1 + 180 * 30 + qoff;
        const float* __restrict__ wy = W1 + 181 * 30 + qoff;
#pragma unroll
        for (int q = 0; q < 8; q++) h1[q] += posx * wx[q];
#pragma unroll
        for (int q = 0; q < 8; q++) h1[q] += posy * wy[q];
#pragma unroll
        for (int q = 0; q < 8; q++) h1[q] = fmaxf(h1[q], 0.0f);
        // publish my slice of h1 (overlapping slices write identical values)
#pragma unroll
        for (int q = 0; q < 8; q++) s_h[cell * HSTRIDE + qoff + q] = h1[q];
    }
    __syncthreads();

    // ---------------- layer 2: 30 -> 30 (this thread: 8 @ qoff) -----------
    float h2[8];
    {
        const float* __restrict__ bb = b2 + qoff;
#pragma unroll
        for (int q = 0; q < 8; q++) h2[q] = bb[q];
    }
    if (active) {
        float a1[30];
#pragma unroll
        for (int k = 0; k < 30; k++) a1[k] = s_h[cell * HSTRIDE + k];
#pragma unroll 2
        for (int k = 0; k < 30; k++) {
            const float* __restrict__ wr = W2 + k * 30 + qoff;
#pragma unroll
            for (int q = 0; q < 8; q++) h2[q] += a1[k] * wr[q];
        }
#pragma unroll
        for (int q = 0; q < 8; q++) h2[q] = fmaxf(h2[q], 0.0f);
    }
    __syncthreads();   // all a1 reads done before overwrite
    if (active) {
#pragma unroll
        for (int q = 0; q < 8; q++) s_h[cell * HSTRIDE + qoff + q] = h2[q];
    }
    __syncthreads();

    // ---------------- layer 3: 30 -> 21 (this thread: 6 @ off3) -----------
    float o[6];
    {
        const float* __restrict__ bb = b3 + off3;
#pragma unroll
        for (int c = 0; c < 6; c++) o[c] = bb[c];
    }
    if (active) {
        float a2[30];
#pragma unroll
        for (int k = 0; k < 30; k++) a2[k] = s_h[cell * HSTRIDE + k];
#pragma unroll 2
        for (int k = 0; k < 30; k++) {
            const float* __restrict__ wr = W3 + k * 21 + off3;
#pragma unroll
            for (int c = 0; c < 6; c++) o[c] += a2[k] * wr[c];
        }

        const int lcenter = ((r + 1) * NPIX + (j + 1)) * CSTATE;
        if (!LAST) {
            float* __restrict__ ns =
                state_new + (((size_t)b * NPIX + (i + 1)) * NPIX + (j + 1)) * CSTATE;
            // disjoint channel slices: q0 -> ch0-5, q1 -> ch6-10,
            // q2 -> ch11-15, q3 -> ch16-18 + movement (ch19,20 = o[4],o[5])
            if (qh == 0) {
#pragma unroll
                for (int c = 0; c < 6; c++)
                    ns[c] = (FIRST ? 0.0f : s_state[lcenter + c]) + o[c];
            } else if (qh < 3) {
#pragma unroll
                for (int c = 1; c < 6; c++)
                    ns[off3 + c] = (FIRST ? 0.0f : s_state[lcenter + off3 + c]) + o[c];
            } else {
#pragma unroll
                for (int c = 1; c < 4; c++)
                    ns[15 + c] = (FIRST ? 0.0f : s_state[lcenter + 15 + c]) + o[c];
                int dxm = (o[4] > THRESHV) ? 1 : ((o[4] < -THRESHV) ? -1 : 0);
                int dym = (o[5] > THRESHV) ? 1 : ((o[5] < -THRESHV) ? -1 : 0);
                px += dxm; py += dym;
                px = (px < 0) ? 0 : ((px > NNEO - 1) ? NNEO - 1 : px);
                py = (py < 0) ? 0 : ((py > NNEO - 1) ? NNEO - 1 : py);
                perc[2 * gcell + 0] = px;
                perc[2 * gcell + 1] = py;
            }
        } else {
            // final step: emit guesses + class_state only
            float* __restrict__ g = guesses_out + (size_t)gcell * OUTD;
            if (qh == 0) {
#pragma unroll
                for (int c = 0; c < 6; c++) g[c] = o[c];
            } else {
#pragma unroll
                for (int c = 1; c < 6; c++) g[off3 + c] = o[c];
            }
            if (qh == 3) {
                // class channels 16..18 = center state + o[1..3]
                float* __restrict__ cs = class_out + (size_t)gcell * 3;
#pragma unroll
                for (int cc = 0; cc < 3; cc++)
                    cs[cc] = s_state[lcenter + 16 + cc] + o[1 + cc];
            }
        }
    }
}

extern "C" void kernel_launch(void* const* d_in, const int* in_sizes, int n_in,
                              void* d_out, int out_size, void* d_ws, size_t ws_size,
                              hipStream_t stream) {
    const float* img = (const float*)d_in[0];
    const float* W1  = (const float*)d_in[1];
    const float* b1  = (const float*)d_in[2];
    const float* W2  = (const float*)d_in[3];
    const float* b2  = (const float*)d_in[4];
    const float* W3  = (const float*)d_in[5];
    const float* b3  = (const float*)d_in[6];

    float* out = (float*)d_out;
    float* class_out   = out;                 // 345,600 floats
    float* guesses_out = out + CLASS_ELEMS;   // 2,419,200 floats

    float* stateA = (float*)d_ws;
    float* stateB = stateA + STATE_ELEMS;
    int*   perc   = (int*)(stateB + STATE_ELEMS);

    {
        const int total = B_ * 124 * CSTATE;
        nca_init<<<(total + 255) / 256, 256, 0, stream>>>(stateA, stateB);
    }

    const dim3 grid(4, B_);
    for (int t = 0; t < ITERS; t++) {
        const float* so = (t & 1) ? stateB : stateA;
        float*       sn = (t & 1) ? stateA : stateB;
        if (t == 0) {
            nca_step<true, false><<<grid, 1024, 0, stream>>>(
                img, W1, b1, W2, b2, W3, b3, so, sn, perc, guesses_out, class_out);
        } else if (t == ITERS - 1) {
            nca_step<false, true><<<grid, 1024, 0, stream>>>(
                img, W1, b1, W2, b2, W3, b3, so, sn, perc, guesses_out, class_out);
        } else {
            nca_step<false, false><<<grid, 1024, 0, stream>>>(
                img, W1, b1, W2, b2, W3, b3, so, sn, perc, guesses_out, class_out);
        }
    }
}

// Round 9
// 366.563 us; speedup vs baseline: 3.2708x; 3.2708x over previous
//
#include <hip/hip_runtime.h>

// Problem constants (from reference)
#define B_      128
#define NPIX    32      // N = M = 32
#define NNEO    30      // N-2
#define CSTATE  19      // state channels
#define OUTD    21      // OUT_DIM
#define ITERS   10
#define THRESHV 0.0007f

#define STATE_ELEMS (B_ * NPIX * NPIX * CSTATE)   // 2,490,368 floats per buffer
#define NCELLS      (B_ * NNEO * NNEO)            // 115,200
#define CLASS_ELEMS (NCELLS * 3)                  // 345,600
#define HSTRIDE 31    // s_h cell stride: gcd(31,32)=1 -> conflict-free

// ---------------------------------------------------------------------------
// init: zero ONLY the borders of both state buffers (interiors are fully
// written by each step before being read). perc needs no init: step t=0
// derives (px,py)=(i,j) itself.
// ---------------------------------------------------------------------------
__global__ void nca_init(float* __restrict__ stateA, float* __restrict__ stateB) {
    int idx = blockIdx.x * blockDim.x + threadIdx.x;
    const int total = B_ * 124 * CSTATE;
    if (idx >= total) return;
    int c  = idx % CSTATE;
    int t2 = idx / CSTATE;
    int cell = t2 % 124;
    int b    = t2 / 124;
    int i, j;
    if (cell < 32)      { i = 0;  j = cell; }
    else if (cell < 64) { i = 31; j = cell - 32; }
    else { int k = cell - 64; i = 1 + (k >> 1); j = (k & 1) ? 31 : 0; }
    size_t off = (((size_t)b * NPIX + i) * NPIX + j) * CSTATE + c;
    stateA[off] = 0.0f;
    stateB[off] = 0.0f;
}

// ---------------------------------------------------------------------------
// One NCA step. Block = (batch b, row-group rg): row groups {8,8,7,7}, 30
// cols, 1024 threads = 4 "quarters" of 4 waves. Quarter qh computes output
// slice [QOFF(qh), QOFF(qh)+8) of layers 1-2 and [5*qh, 5*qh+6) of layer 3.
// 8 waves/SIMD (32 waves/CU = HW cap). VGPR budget is 64 (launch_bounds 8
// waves/EU) — live-set headroom over the rolled baseline is ~12 regs.
// CODEGEN RULES (R3-R8 lessons):
//  - NO #pragma unroll on weight loops: unroll-all (R6) and unroll-2 (R8)
//    both collapsed the allocator (VGPR 16-32, 120-430 MB/step scratch).
//    Root cause: layer 2's a1[30] makes any duplication blow the 64 budget.
//  - Layer-1 pairing is done MANUALLY below (explicit w0/w1, rolled pair
//    loop, fv read per-pair from LDS): ~40-45 live regs, fits the budget,
//    halves the s_load drains in the 78%-of-FLOPs loop.
//  - ROW-MAJOR s_state + float4 staging ONLY (channel-major broke
//    post-timing validation in R7 with zero perf gain).
// ---------------------------------------------------------------------------
template<bool FIRST, bool LAST>
__global__ __launch_bounds__(1024, 8)
void nca_step(const float* __restrict__ img,
              const float* __restrict__ W1, const float* __restrict__ b1,
              const float* __restrict__ W2, const float* __restrict__ b2,
              const float* __restrict__ W3, const float* __restrict__ b3,
              const float* __restrict__ state_old, float* __restrict__ state_new,
              int* perc, float* __restrict__ guesses_out,
              float* __restrict__ class_out) {
    __shared__ float s_state[10 * NPIX * CSTATE];   // 6080 floats = 24.3 KB
    __shared__ float s_img[NPIX * NPIX];            // 1024 floats = 4 KB
    __shared__ float s_h[240 * HSTRIDE];            // 7440 floats = 29.8 KB

    const int b   = blockIdx.y;
    const int rg  = blockIdx.x;
    const int i0  = (rg < 2) ? rg * 8 : 16 + (rg - 2) * 7;
    const int nr  = (rg < 2) ? 8 : 7;
    const int tid = threadIdx.x;
    const int qh  = __builtin_amdgcn_readfirstlane(tid >> 8);   // wave-uniform
    const int cell = tid & 255;
    const int qoff = (qh == 0) ? 0 : (qh == 1) ? 8 : (qh == 2) ? 14 : 22;
    const int off3 = 5 * qh;

    // --- stage state rows [i0, i0+nr+2) and the full image into LDS ---
    if (!FIRST) {
        const int n4 = (nr + 2) * NPIX * CSTATE / 4;   // divisible by 4
        const float4* gstate4 =
            (const float4*)(state_old + ((size_t)b * NPIX + i0) * NPIX * CSTATE);
        float4* s_state4 = (float4*)s_state;
        for (int t = tid; t < n4; t += 1024) s_state4[t] = gstate4[t];
    }
    if (tid < NPIX * NPIX / 4) {
        ((float4*)s_img)[tid] = ((const float4*)(img + (size_t)b * NPIX * NPIX))[tid];
    }
    __syncthreads();

    const int cells = nr * NNEO;
    const bool active = cell < cells;

    int r = 0, j = 0, i = 0, gcell = 0, px = 0, py = 0;
    if (active) {
        r = cell / NNEO;
        j = cell % NNEO;
        i = i0 + r;
        gcell = (b * NNEO + i) * NNEO + j;
        if (FIRST) { px = i; py = j; }
        else       { px = perc[2 * gcell]; py = perc[2 * gcell + 1]; }
    }

    // ---------------- layer 1: 182 -> 30 (this thread: 8 @ qoff) ----------
    float h1[8];
    {
        const float* __restrict__ bb = b1 + qoff;
#pragma unroll
        for (int q = 0; q < 8; q++) h1[q] = bb[q];
    }
    if (active) {
        for (int pr = 0; pr < 3; pr++) {
            for (int pc = 0; pc < 3; pc++) {
                const int p9 = pr * 3 + pc;
                const float iv = s_img[(px + pr) * NPIX + (py + pc)];
                const float* __restrict__ wp = W1 + (p9 * 20) * 30 + qoff;
                // row 0: image feature
#pragma unroll
                for (int q = 0; q < 8; q++) h1[q] += iv * wp[q];
                if (!FIRST) {
                    const int sbase = ((r + pr) * NPIX + (j + pc)) * CSTATE;
                    // rows 1..19, manually paired: two independent s_load
                    // rows per drain; fv pair via ds_read2 off one vaddr.
                    // Rolled pair loop (9 iters) — do NOT add unroll pragmas.
                    for (int ch = 0; ch < 18; ch += 2) {
                        const float f0 = s_state[sbase + ch];
                        const float f1 = s_state[sbase + ch + 1];
                        const float* __restrict__ wr0 = wp + (ch + 1) * 30;
                        const float* __restrict__ wr1 = wp + (ch + 2) * 30;
                        float w0[8], w1[8];
#pragma unroll
                        for (int q = 0; q < 8; q++) w0[q] = wr0[q];
#pragma unroll
                        for (int q = 0; q < 8; q++) w1[q] = wr1[q];
#pragma unroll
                        for (int q = 0; q < 8; q++) h1[q] += f0 * w0[q];
#pragma unroll
                        for (int q = 0; q < 8; q++) h1[q] += f1 * w1[q];
                    }
                    {   // tail: ch = 18
                        const float f18 = s_state[sbase + 18];
                        const float* __restrict__ wr = wp + 19 * 30;
#pragma unroll
                        for (int q = 0; q < 8; q++) h1[q] += f18 * wr[q];
                    }
                }
            }
        }
        const float posx = (float)(px - 16) * (1.0f / 16.0f);
        const float posy = (float)(py - 16) * (1.0f / 16.0f);
        const float* __restrict__ wx = W1 + 180 * 30 + qoff;
        const float* __restrict__ wy = W1 + 181 * 30 + qoff;
#pragma unroll
        for (int q = 0; q < 8; q++) h1[q] += posx * wx[q];
#pragma unroll
        for (int q = 0; q < 8; q++) h1[q] += posy * wy[q];
#pragma unroll
        for (int q = 0; q < 8; q++) h1[q] = fmaxf(h1[q], 0.0f);
        // publish my slice of h1 (overlapping slices write identical values)
#pragma unroll
        for (int q = 0; q < 8; q++) s_h[cell * HSTRIDE + qoff + q] = h1[q];
    }
    __syncthreads();

    // ---------------- layer 2: 30 -> 30 (this thread: 8 @ qoff) -----------
    float h2[8];
    {
        const float* __restrict__ bb = b2 + qoff;
#pragma unroll
        for (int q = 0; q < 8; q++) h2[q] = bb[q];
    }
    if (active) {
        float a1[30];
#pragma unroll
        for (int k = 0; k < 30; k++) a1[k] = s_h[cell * HSTRIDE + k];
        for (int k = 0; k < 30; k++) {
            const float* __restrict__ wr = W2 + k * 30 + qoff;
#pragma unroll
            for (int q = 0; q < 8; q++) h2[q] += a1[k] * wr[q];
        }
#pragma unroll
        for (int q = 0; q < 8; q++) h2[q] = fmaxf(h2[q], 0.0f);
    }
    __syncthreads();   // all a1 reads done before overwrite
    if (active) {
#pragma unroll
        for (int q = 0; q < 8; q++) s_h[cell * HSTRIDE + qoff + q] = h2[q];
    }
    __syncthreads();

    // ---------------- layer 3: 30 -> 21 (this thread: 6 @ off3) -----------
    float o[6];
    {
        const float* __restrict__ bb = b3 + off3;
#pragma unroll
        for (int c = 0; c < 6; c++) o[c] = bb[c];
    }
    if (active) {
        float a2[30];
#pragma unroll
        for (int k = 0; k < 30; k++) a2[k] = s_h[cell * HSTRIDE + k];
        for (int k = 0; k < 30; k++) {
            const float* __restrict__ wr = W3 + k * 21 + off3;
#pragma unroll
            for (int c = 0; c < 6; c++) o[c] += a2[k] * wr[c];
        }

        const int lcenter = ((r + 1) * NPIX + (j + 1)) * CSTATE;
        if (!LAST) {
            float* __restrict__ ns =
                state_new + (((size_t)b * NPIX + (i + 1)) * NPIX + (j + 1)) * CSTATE;
            // disjoint channel slices: q0 -> ch0-5, q1 -> ch6-10,
            // q2 -> ch11-15, q3 -> ch16-18 + movement (ch19,20 = o[4],o[5])
            if (qh == 0) {
#pragma unroll
                for (int c = 0; c < 6; c++)
                    ns[c] = (FIRST ? 0.0f : s_state[lcenter + c]) + o[c];
            } else if (qh < 3) {
#pragma unroll
                for (int c = 1; c < 6; c++)
                    ns[off3 + c] = (FIRST ? 0.0f : s_state[lcenter + off3 + c]) + o[c];
            } else {
#pragma unroll
                for (int c = 1; c < 4; c++)
                    ns[15 + c] = (FIRST ? 0.0f : s_state[lcenter + 15 + c]) + o[c];
                int dxm = (o[4] > THRESHV) ? 1 : ((o[4] < -THRESHV) ? -1 : 0);
                int dym = (o[5] > THRESHV) ? 1 : ((o[5] < -THRESHV) ? -1 : 0);
                px += dxm; py += dym;
                px = (px < 0) ? 0 : ((px > NNEO - 1) ? NNEO - 1 : px);
                py = (py < 0) ? 0 : ((py > NNEO - 1) ? NNEO - 1 : py);
                perc[2 * gcell + 0] = px;
                perc[2 * gcell + 1] = py;
            }
        } else {
            // final step: emit guesses + class_state only
            float* __restrict__ g = guesses_out + (size_t)gcell * OUTD;
            if (qh == 0) {
#pragma unroll
                for (int c = 0; c < 6; c++) g[c] = o[c];
            } else {
#pragma unroll
                for (int c = 1; c < 6; c++) g[off3 + c] = o[c];
            }
            if (qh == 3) {
                // class channels 16..18 = center state + o[1..3]
                float* __restrict__ cs = class_out + (size_t)gcell * 3;
#pragma unroll
                for (int cc = 0; cc < 3; cc++)
                    cs[cc] = s_state[lcenter + 16 + cc] + o[1 + cc];
            }
        }
    }
}

extern "C" void kernel_launch(void* const* d_in, const int* in_sizes, int n_in,
                              void* d_out, int out_size, void* d_ws, size_t ws_size,
                              hipStream_t stream) {
    const float* img = (const float*)d_in[0];
    const float* W1  = (const float*)d_in[1];
    const float* b1  = (const float*)d_in[2];
    const float* W2  = (const float*)d_in[3];
    const float* b2  = (const float*)d_in[4];
    const float* W3  = (const float*)d_in[5];
    const float* b3  = (const float*)d_in[6];

    float* out = (float*)d_out;
    float* class_out   = out;                 // 345,600 floats
    float* guesses_out = out + CLASS_ELEMS;   // 2,419,200 floats

    float* stateA = (float*)d_ws;
    float* stateB = stateA + STATE_ELEMS;
    int*   perc   = (int*)(stateB + STATE_ELEMS);

    {
        const int total = B_ * 124 * CSTATE;
        nca_init<<<(total + 255) / 256, 256, 0, stream>>>(stateA, stateB);
    }

    const dim3 grid(4, B_);
    for (int t = 0; t < ITERS; t++) {
        const float* so = (t & 1) ? stateB : stateA;
        float*       sn = (t & 1) ? stateA : stateB;
        if (t == 0) {
            nca_step<true, false><<<grid, 1024, 0, stream>>>(
                img, W1, b1, W2, b2, W3, b3, so, sn, perc, guesses_out, class_out);
        } else if (t == ITERS - 1) {
            nca_step<false, true><<<grid, 1024, 0, stream>>>(
                img, W1, b1, W2, b2, W3, b3, so, sn, perc, guesses_out, class_out);
        } else {
            nca_step<false, false><<<grid, 1024, 0, stream>>>(
                img, W1, b1, W2, b2, W3, b3, so, sn, perc, guesses_out, class_out);
        }
    }
}

// Round 10
// 366.296 us; speedup vs baseline: 3.2732x; 1.0007x over previous
//
#include <hip/hip_runtime.h>

// Problem constants (from reference)
#define B_      128
#define NPIX    32      // N = M = 32
#define NNEO    30      // N-2
#define CSTATE  19      // state channels
#define OUTD    21      // OUT_DIM
#define ITERS   10
#define THRESHV 0.0007f

#define STATE_ELEMS (B_ * NPIX * NPIX * CSTATE)   // 2,490,368 floats per buffer
#define NCELLS      (B_ * NNEO * NNEO)            // 115,200
#define CLASS_ELEMS (NCELLS * 3)                  // 345,600
#define HSTRIDE 31    // s_h cell stride: gcd(31,32)=1 -> conflict-free

// ---------------------------------------------------------------------------
// init: zero ONLY the borders of both state buffers (interiors are fully
// written by each step before being read). perc needs no init: step 0
// derives (px,py)=(i,j) itself.
// ---------------------------------------------------------------------------
__global__ void nca_init(float* __restrict__ stateA, float* __restrict__ stateB) {
    int idx = blockIdx.x * blockDim.x + threadIdx.x;
    const int total = B_ * 124 * CSTATE;
    if (idx >= total) return;
    int c  = idx % CSTATE;
    int t2 = idx / CSTATE;
    int cell = t2 % 124;
    int b    = t2 / 124;
    int i, j;
    if (cell < 32)      { i = 0;  j = cell; }
    else if (cell < 64) { i = 31; j = cell - 32; }
    else { int k = cell - 64; i = 1 + (k >> 1); j = (k & 1) ? 31 : 0; }
    size_t off = (((size_t)b * NPIX + i) * NPIX + j) * CSTATE + c;
    stateA[off] = 0.0f;
    stateB[off] = 0.0f;
}

// ---------------------------------------------------------------------------
// Step 0 as a STANDALONE kernel. R6/R9 evidence: the FIRST=true template
// instantiation repeatedly gets a degenerate register allocation (R9: 136us,
// VGPR 32, VALUBusy 8% — for the LIGHTEST variant). A dedicated kernel with
// no s_state array removes that instantiation entirely. State is all-zero at
// t=0, so h1 = b1 + sum_p9 iv*W1row0(p9) + pos terms; layers 2/3 full.
// ---------------------------------------------------------------------------
__global__ __launch_bounds__(1024, 8)
void nca_step0(const float* __restrict__ img,
               const float* __restrict__ W1, const float* __restrict__ b1,
               const float* __restrict__ W2, const float* __restrict__ b2,
               const float* __restrict__ W3, const float* __restrict__ b3,
               float* __restrict__ state_new, int* __restrict__ perc) {
    __shared__ float s_img[NPIX * NPIX];            // 4 KB
    __shared__ float s_h[240 * HSTRIDE];            // 29.8 KB

    const int b   = blockIdx.y;
    const int rg  = blockIdx.x;
    const int i0  = (rg < 2) ? rg * 8 : 16 + (rg - 2) * 7;
    const int nr  = (rg < 2) ? 8 : 7;
    const int tid = threadIdx.x;
    const int qh  = __builtin_amdgcn_readfirstlane(tid >> 8);   // wave-uniform
    const int cell = tid & 255;
    const int qoff = (qh == 0) ? 0 : (qh == 1) ? 8 : (qh == 2) ? 14 : 22;
    const int off3 = 5 * qh;

    if (tid < NPIX * NPIX / 4) {
        ((float4*)s_img)[tid] = ((const float4*)(img + (size_t)b * NPIX * NPIX))[tid];
    }
    __syncthreads();

    const int cells = nr * NNEO;
    const bool active = cell < cells;

    int r = 0, j = 0, i = 0, gcell = 0, px = 0, py = 0;
    if (active) {
        r = cell / NNEO;
        j = cell % NNEO;
        i = i0 + r;
        gcell = (b * NNEO + i) * NNEO + j;
        px = i; py = j;
    }

    // layer 1 (no state terms at t=0)
    float h1[8];
    {
        const float* __restrict__ bb = b1 + qoff;
#pragma unroll
        for (int q = 0; q < 8; q++) h1[q] = bb[q];
    }
    if (active) {
        for (int pr = 0; pr < 3; pr++) {
            for (int pc = 0; pc < 3; pc++) {
                const int p9 = pr * 3 + pc;
                const float iv = s_img[(px + pr) * NPIX + (py + pc)];
                const float* __restrict__ wp = W1 + (p9 * 20) * 30 + qoff;
#pragma unroll
                for (int q = 0; q < 8; q++) h1[q] += iv * wp[q];
            }
        }
        const float posx = (float)(px - 16) * (1.0f / 16.0f);
        const float posy = (float)(py - 16) * (1.0f / 16.0f);
        const float* __restrict__ wx = W1 + 180 * 30 + qoff;
        const float* __restrict__ wy = W1 + 181 * 30 + qoff;
#pragma unroll
        for (int q = 0; q < 8; q++) h1[q] += posx * wx[q];
#pragma unroll
        for (int q = 0; q < 8; q++) h1[q] += posy * wy[q];
#pragma unroll
        for (int q = 0; q < 8; q++) h1[q] = fmaxf(h1[q], 0.0f);
#pragma unroll
        for (int q = 0; q < 8; q++) s_h[cell * HSTRIDE + qoff + q] = h1[q];
    }
    __syncthreads();

    // layer 2
    float h2[8];
    {
        const float* __restrict__ bb = b2 + qoff;
#pragma unroll
        for (int q = 0; q < 8; q++) h2[q] = bb[q];
    }
    if (active) {
        float a1[30];
#pragma unroll
        for (int k = 0; k < 30; k++) a1[k] = s_h[cell * HSTRIDE + k];
        for (int k = 0; k < 30; k++) {
            const float* __restrict__ wr = W2 + k * 30 + qoff;
#pragma unroll
            for (int q = 0; q < 8; q++) h2[q] += a1[k] * wr[q];
        }
#pragma unroll
        for (int q = 0; q < 8; q++) h2[q] = fmaxf(h2[q], 0.0f);
    }
    __syncthreads();
    if (active) {
#pragma unroll
        for (int q = 0; q < 8; q++) s_h[cell * HSTRIDE + qoff + q] = h2[q];
    }
    __syncthreads();

    // layer 3
    float o[6];
    {
        const float* __restrict__ bb = b3 + off3;
#pragma unroll
        for (int c = 0; c < 6; c++) o[c] = bb[c];
    }
    if (active) {
        float a2[30];
#pragma unroll
        for (int k = 0; k < 30; k++) a2[k] = s_h[cell * HSTRIDE + k];
        for (int k = 0; k < 30; k++) {
            const float* __restrict__ wr = W3 + k * 21 + off3;
#pragma unroll
            for (int c = 0; c < 6; c++) o[c] += a2[k] * wr[c];
        }
        float* __restrict__ ns =
            state_new + (((size_t)b * NPIX + (i + 1)) * NPIX + (j + 1)) * CSTATE;
        if (qh == 0) {
#pragma unroll
            for (int c = 0; c < 6; c++) ns[c] = o[c];
        } else if (qh < 3) {
#pragma unroll
            for (int c = 1; c < 6; c++) ns[off3 + c] = o[c];
        } else {
#pragma unroll
            for (int c = 1; c < 4; c++) ns[15 + c] = o[c];
            int dxm = (o[4] > THRESHV) ? 1 : ((o[4] < -THRESHV) ? -1 : 0);
            int dym = (o[5] > THRESHV) ? 1 : ((o[5] < -THRESHV) ? -1 : 0);
            px += dxm; py += dym;
            px = (px < 0) ? 0 : ((px > NNEO - 1) ? NNEO - 1 : px);
            py = (py < 0) ? 0 : ((py > NNEO - 1) ? NNEO - 1 : py);
            perc[2 * gcell + 0] = px;
            perc[2 * gcell + 1] = py;
        }
    }
}

// ---------------------------------------------------------------------------
// Steps 1..9. Identical body to the R9 passing kernel (manual layer-1
// pairing), templated ONLY on LAST. CODEGEN RULES (R3-R9):
//  - NO #pragma unroll on weight loops (R6/R8 spill catastrophes).
//  - Manual pairing only in layer 1 (fits the 64-VGPR budget).
//  - ROW-MAJOR s_state + float4 staging (channel-major broke validation).
//  - FIRST-step logic lives in nca_step0 (template instantiation pathology).
// ---------------------------------------------------------------------------
template<bool LAST>
__global__ __launch_bounds__(1024, 8)
void nca_step(const float* __restrict__ img,
              const float* __restrict__ W1, const float* __restrict__ b1,
              const float* __restrict__ W2, const float* __restrict__ b2,
              const float* __restrict__ W3, const float* __restrict__ b3,
              const float* __restrict__ state_old, float* __restrict__ state_new,
              int* perc, float* __restrict__ guesses_out,
              float* __restrict__ class_out) {
    __shared__ float s_state[10 * NPIX * CSTATE];   // 24.3 KB
    __shared__ float s_img[NPIX * NPIX];            // 4 KB
    __shared__ float s_h[240 * HSTRIDE];            // 29.8 KB

    const int b   = blockIdx.y;
    const int rg  = blockIdx.x;
    const int i0  = (rg < 2) ? rg * 8 : 16 + (rg - 2) * 7;
    const int nr  = (rg < 2) ? 8 : 7;
    const int tid = threadIdx.x;
    const int qh  = __builtin_amdgcn_readfirstlane(tid >> 8);   // wave-uniform
    const int cell = tid & 255;
    const int qoff = (qh == 0) ? 0 : (qh == 1) ? 8 : (qh == 2) ? 14 : 22;
    const int off3 = 5 * qh;

    {
        const int n4 = (nr + 2) * NPIX * CSTATE / 4;   // divisible by 4
        const float4* gstate4 =
            (const float4*)(state_old + ((size_t)b * NPIX + i0) * NPIX * CSTATE);
        float4* s_state4 = (float4*)s_state;
        for (int t = tid; t < n4; t += 1024) s_state4[t] = gstate4[t];
    }
    if (tid < NPIX * NPIX / 4) {
        ((float4*)s_img)[tid] = ((const float4*)(img + (size_t)b * NPIX * NPIX))[tid];
    }
    __syncthreads();

    const int cells = nr * NNEO;
    const bool active = cell < cells;

    int r = 0, j = 0, i = 0, gcell = 0, px = 0, py = 0;
    if (active) {
        r = cell / NNEO;
        j = cell % NNEO;
        i = i0 + r;
        gcell = (b * NNEO + i) * NNEO + j;
        px = perc[2 * gcell]; py = perc[2 * gcell + 1];
    }

    // ---------------- layer 1: 182 -> 30 (this thread: 8 @ qoff) ----------
    float h1[8];
    {
        const float* __restrict__ bb = b1 + qoff;
#pragma unroll
        for (int q = 0; q < 8; q++) h1[q] = bb[q];
    }
    if (active) {
        for (int pr = 0; pr < 3; pr++) {
            for (int pc = 0; pc < 3; pc++) {
                const int p9 = pr * 3 + pc;
                const float iv = s_img[(px + pr) * NPIX + (py + pc)];
                const float* __restrict__ wp = W1 + (p9 * 20) * 30 + qoff;
#pragma unroll
                for (int q = 0; q < 8; q++) h1[q] += iv * wp[q];
                const int sbase = ((r + pr) * NPIX + (j + pc)) * CSTATE;
                // rows 1..19, manually paired; rolled pair loop — no pragmas.
                for (int ch = 0; ch < 18; ch += 2) {
                    const float f0 = s_state[sbase + ch];
                    const float f1 = s_state[sbase + ch + 1];
                    const float* __restrict__ wr0 = wp + (ch + 1) * 30;
                    const float* __restrict__ wr1 = wp + (ch + 2) * 30;
                    float w0[8], w1[8];
#pragma unroll
                    for (int q = 0; q < 8; q++) w0[q] = wr0[q];
#pragma unroll
                    for (int q = 0; q < 8; q++) w1[q] = wr1[q];
#pragma unroll
                    for (int q = 0; q < 8; q++) h1[q] += f0 * w0[q];
#pragma unroll
                    for (int q = 0; q < 8; q++) h1[q] += f1 * w1[q];
                }
                {   // tail: ch = 18
                    const float f18 = s_state[sbase + 18];
                    const float* __restrict__ wr = wp + 19 * 30;
#pragma unroll
                    for (int q = 0; q < 8; q++) h1[q] += f18 * wr[q];
                }
            }
        }
        const float posx = (float)(px - 16) * (1.0f / 16.0f);
        const float posy = (float)(py - 16) * (1.0f / 16.0f);
        const float* __restrict__ wx = W1 + 180 * 30 + qoff;
        const float* __restrict__ wy = W1 + 181 * 30 + qoff;
#pragma unroll
        for (int q = 0; q < 8; q++) h1[q] += posx * wx[q];
#pragma unroll
        for (int q = 0; q < 8; q++) h1[q] += posy * wy[q];
#pragma unroll
        for (int q = 0; q < 8; q++) h1[q] = fmaxf(h1[q], 0.0f);
#pragma unroll
        for (int q = 0; q < 8; q++) s_h[cell * HSTRIDE + qoff + q] = h1[q];
    }
    __syncthreads();

    // ---------------- layer 2: 30 -> 30 (this thread: 8 @ qoff) -----------
    float h2[8];
    {
        const float* __restrict__ bb = b2 + qoff;
#pragma unroll
        for (int q = 0; q < 8; q++) h2[q] = bb[q];
    }
    if (active) {
        float a1[30];
#pragma unroll
        for (int k = 0; k < 30; k++) a1[k] = s_h[cell * HSTRIDE + k];
        for (int k = 0; k < 30; k++) {
            const float* __restrict__ wr = W2 + k * 30 + qoff;
#pragma unroll
            for (int q = 0; q < 8; q++) h2[q] += a1[k] * wr[q];
        }
#pragma unroll
        for (int q = 0; q < 8; q++) h2[q] = fmaxf(h2[q], 0.0f);
    }
    __syncthreads();   // all a1 reads done before overwrite
    if (active) {
#pragma unroll
        for (int q = 0; q < 8; q++) s_h[cell * HSTRIDE + qoff + q] = h2[q];
    }
    __syncthreads();

    // ---------------- layer 3: 30 -> 21 (this thread: 6 @ off3) -----------
    float o[6];
    {
        const float* __restrict__ bb = b3 + off3;
#pragma unroll
        for (int c = 0; c < 6; c++) o[c] = bb[c];
    }
    if (active) {
        float a2[30];
#pragma unroll
        for (int k = 0; k < 30; k++) a2[k] = s_h[cell * HSTRIDE + k];
        for (int k = 0; k < 30; k++) {
            const float* __restrict__ wr = W3 + k * 21 + off3;
#pragma unroll
            for (int c = 0; c < 6; c++) o[c] += a2[k] * wr[c];
        }

        const int lcenter = ((r + 1) * NPIX + (j + 1)) * CSTATE;
        if (!LAST) {
            float* __restrict__ ns =
                state_new + (((size_t)b * NPIX + (i + 1)) * NPIX + (j + 1)) * CSTATE;
            if (qh == 0) {
#pragma unroll
                for (int c = 0; c < 6; c++)
                    ns[c] = s_state[lcenter + c] + o[c];
            } else if (qh < 3) {
#pragma unroll
                for (int c = 1; c < 6; c++)
                    ns[off3 + c] = s_state[lcenter + off3 + c] + o[c];
            } else {
#pragma unroll
                for (int c = 1; c < 4; c++)
                    ns[15 + c] = s_state[lcenter + 15 + c] + o[c];
                int dxm = (o[4] > THRESHV) ? 1 : ((o[4] < -THRESHV) ? -1 : 0);
                int dym = (o[5] > THRESHV) ? 1 : ((o[5] < -THRESHV) ? -1 : 0);
                px += dxm; py += dym;
                px = (px < 0) ? 0 : ((px > NNEO - 1) ? NNEO - 1 : px);
                py = (py < 0) ? 0 : ((py > NNEO - 1) ? NNEO - 1 : py);
                perc[2 * gcell + 0] = px;
                perc[2 * gcell + 1] = py;
            }
        } else {
            float* __restrict__ g = guesses_out + (size_t)gcell * OUTD;
            if (qh == 0) {
#pragma unroll
                for (int c = 0; c < 6; c++) g[c] = o[c];
            } else {
#pragma unroll
                for (int c = 1; c < 6; c++) g[off3 + c] = o[c];
            }
            if (qh == 3) {
                float* __restrict__ cs = class_out + (size_t)gcell * 3;
#pragma unroll
                for (int cc = 0; cc < 3; cc++)
                    cs[cc] = s_state[lcenter + 16 + cc] + o[1 + cc];
            }
        }
    }
}

extern "C" void kernel_launch(void* const* d_in, const int* in_sizes, int n_in,
                              void* d_out, int out_size, void* d_ws, size_t ws_size,
                              hipStream_t stream) {
    const float* img = (const float*)d_in[0];
    const float* W1  = (const float*)d_in[1];
    const float* b1  = (const float*)d_in[2];
    const float* W2  = (const float*)d_in[3];
    const float* b2  = (const float*)d_in[4];
    const float* W3  = (const float*)d_in[5];
    const float* b3  = (const float*)d_in[6];

    float* out = (float*)d_out;
    float* class_out   = out;                 // 345,600 floats
    float* guesses_out = out + CLASS_ELEMS;   // 2,419,200 floats

    float* stateA = (float*)d_ws;
    float* stateB = stateA + STATE_ELEMS;
    int*   perc   = (int*)(stateB + STATE_ELEMS);

    {
        const int total = B_ * 124 * CSTATE;
        nca_init<<<(total + 255) / 256, 256, 0, stream>>>(stateA, stateB);
    }

    const dim3 grid(4, B_);
    // t = 0: standalone kernel, writes stateB (so=A unused), sets perc
    nca_step0<<<grid, 1024, 0, stream>>>(img, W1, b1, W2, b2, W3, b3,
                                         stateB, perc);
    // t = 1..8: mid steps
    for (int t = 1; t < ITERS - 1; t++) {
        const float* so = (t & 1) ? stateB : stateA;
        float*       sn = (t & 1) ? stateA : stateB;
        nca_step<false><<<grid, 1024, 0, stream>>>(
            img, W1, b1, W2, b2, W3, b3, so, sn, perc, guesses_out, class_out);
    }
    // t = 9 (odd): reads stateB, emits outputs only
    nca_step<true><<<grid, 1024, 0, stream>>>(
        img, W1, b1, W2, b2, W3, b3, stateB, stateA, perc, guesses_out, class_out);
}

// Round 11
// 346.567 us; speedup vs baseline: 3.4596x; 1.0569x over previous
//
#include <hip/hip_runtime.h>

// Problem constants (from reference)
#define B_      128
#define NPIX    32      // N = M = 32
#define NNEO    30      // N-2
#define CSTATE  19      // real state channels
#define CPAD    20      // padded channel stride (16B-aligned pixel blocks)
#define OUTD    21      // OUT_DIM
#define ITERS   10
#define THRESHV 0.0007f

#define STATE_ELEMS_PAD (B_ * NPIX * NPIX * CPAD)  // 2,621,440 floats per buffer
#define NCELLS      (B_ * NNEO * NNEO)             // 115,200
#define CLASS_ELEMS (NCELLS * 3)                   // 345,600
#define HSTRIDE 31    // s_h cell stride: gcd(31,32)=1 -> conflict-free

// ---------------------------------------------------------------------------
// init: zero ONLY the borders of both (padded) state buffers. Interior pixels
// are fully written by each step before being read (garbage pad channel 19 is
// read-and-discarded, never used in arithmetic). perc needs no init.
// ---------------------------------------------------------------------------
__global__ void nca_init(float* __restrict__ stateA, float* __restrict__ stateB) {
    int idx = blockIdx.x * blockDim.x + threadIdx.x;
    const int total = B_ * 124 * CPAD;
    if (idx >= total) return;
    int c  = idx % CPAD;
    int t2 = idx / CPAD;
    int cell = t2 % 124;
    int b    = t2 / 124;
    int i, j;
    if (cell < 32)      { i = 0;  j = cell; }
    else if (cell < 64) { i = 31; j = cell - 32; }
    else { int k = cell - 64; i = 1 + (k >> 1); j = (k & 1) ? 31 : 0; }
    size_t off = (((size_t)b * NPIX + i) * NPIX + j) * CPAD + c;
    stateA[off] = 0.0f;
    stateB[off] = 0.0f;
}

// ---------------------------------------------------------------------------
// Step 0 standalone (R9/R10: removes the FIRST-template instantiation that
// kept drawing a degenerate register allocation). State all-zero at t=0.
// ---------------------------------------------------------------------------
__global__ __launch_bounds__(1024, 8)
void nca_step0(const float* __restrict__ img,
               const float* __restrict__ W1, const float* __restrict__ b1,
               const float* __restrict__ W2, const float* __restrict__ b2,
               const float* __restrict__ W3, const float* __restrict__ b3,
               float* __restrict__ state_new, int* __restrict__ perc) {
    __shared__ float s_img[NPIX * NPIX];            // 4 KB
    __shared__ float s_h[240 * HSTRIDE];            // 29.8 KB

    const int b   = blockIdx.y;
    const int rg  = blockIdx.x;
    const int i0  = (rg < 2) ? rg * 8 : 16 + (rg - 2) * 7;
    const int nr  = (rg < 2) ? 8 : 7;
    const int tid = threadIdx.x;
    const int qh  = __builtin_amdgcn_readfirstlane(tid >> 8);   // wave-uniform
    const int cell = tid & 255;
    const int qoff = (qh == 0) ? 0 : (qh == 1) ? 8 : (qh == 2) ? 14 : 22;
    const int off3 = 5 * qh;

    if (tid < NPIX * NPIX / 4) {
        ((float4*)s_img)[tid] = ((const float4*)(img + (size_t)b * NPIX * NPIX))[tid];
    }
    __syncthreads();

    const int cells = nr * NNEO;
    const bool active = cell < cells;

    int r = 0, j = 0, i = 0, gcell = 0, px = 0, py = 0;
    if (active) {
        r = cell / NNEO;
        j = cell % NNEO;
        i = i0 + r;
        gcell = (b * NNEO + i) * NNEO + j;
        px = i; py = j;
    }

    float h1[8];
    {
        const float* __restrict__ bb = b1 + qoff;
#pragma unroll
        for (int q = 0; q < 8; q++) h1[q] = bb[q];
    }
    if (active) {
        for (int pr = 0; pr < 3; pr++) {
            for (int pc = 0; pc < 3; pc++) {
                const int p9 = pr * 3 + pc;
                const float iv = s_img[(px + pr) * NPIX + (py + pc)];
                const float* __restrict__ wp = W1 + (p9 * 20) * 30 + qoff;
#pragma unroll
                for (int q = 0; q < 8; q++) h1[q] += iv * wp[q];
            }
        }
        const float posx = (float)(px - 16) * (1.0f / 16.0f);
        const float posy = (float)(py - 16) * (1.0f / 16.0f);
        const float* __restrict__ wx = W1 + 180 * 30 + qoff;
        const float* __restrict__ wy = W1 + 181 * 30 + qoff;
#pragma unroll
        for (int q = 0; q < 8; q++) h1[q] += posx * wx[q];
#pragma unroll
        for (int q = 0; q < 8; q++) h1[q] += posy * wy[q];
#pragma unroll
        for (int q = 0; q < 8; q++) h1[q] = fmaxf(h1[q], 0.0f);
#pragma unroll
        for (int q = 0; q < 8; q++) s_h[cell * HSTRIDE + qoff + q] = h1[q];
    }
    __syncthreads();

    float h2[8];
    {
        const float* __restrict__ bb = b2 + qoff;
#pragma unroll
        for (int q = 0; q < 8; q++) h2[q] = bb[q];
    }
    if (active) {
        float a1[30];
#pragma unroll
        for (int k = 0; k < 30; k++) a1[k] = s_h[cell * HSTRIDE + k];
        for (int k = 0; k < 30; k++) {
            const float* __restrict__ wr = W2 + k * 30 + qoff;
#pragma unroll
            for (int q = 0; q < 8; q++) h2[q] += a1[k] * wr[q];
        }
#pragma unroll
        for (int q = 0; q < 8; q++) h2[q] = fmaxf(h2[q], 0.0f);
    }
    __syncthreads();
    if (active) {
#pragma unroll
        for (int q = 0; q < 8; q++) s_h[cell * HSTRIDE + qoff + q] = h2[q];
    }
    __syncthreads();

    float o[6];
    {
        const float* __restrict__ bb = b3 + off3;
#pragma unroll
        for (int c = 0; c < 6; c++) o[c] = bb[c];
    }
    if (active) {
        float a2[30];
#pragma unroll
        for (int k = 0; k < 30; k++) a2[k] = s_h[cell * HSTRIDE + k];
        for (int k = 0; k < 30; k++) {
            const float* __restrict__ wr = W3 + k * 21 + off3;
#pragma unroll
            for (int c = 0; c < 6; c++) o[c] += a2[k] * wr[c];
        }
        float* __restrict__ ns =
            state_new + (((size_t)b * NPIX + (i + 1)) * NPIX + (j + 1)) * CPAD;
        if (qh == 0) {
#pragma unroll
            for (int c = 0; c < 6; c++) ns[c] = o[c];
        } else if (qh < 3) {
#pragma unroll
            for (int c = 1; c < 6; c++) ns[off3 + c] = o[c];
        } else {
#pragma unroll
            for (int c = 1; c < 4; c++) ns[15 + c] = o[c];
            int dxm = (o[4] > THRESHV) ? 1 : ((o[4] < -THRESHV) ? -1 : 0);
            int dym = (o[5] > THRESHV) ? 1 : ((o[5] < -THRESHV) ? -1 : 0);
            px += dxm; py += dym;
            px = (px < 0) ? 0 : ((px > NNEO - 1) ? NNEO - 1 : px);
            py = (py < 0) ? 0 : ((py > NNEO - 1) ? NNEO - 1 : py);
            perc[2 * gcell + 0] = px;
            perc[2 * gcell + 1] = py;
        }
    }
}

// ---------------------------------------------------------------------------
// Steps 1..9. R5 proven structure; NEW this round: state is CPAD=20-strided
// everywhere (global + LDS), so the 19 per-position fv reads become 5
// ds_read_b128 (16B-aligned, 2-way bank aliasing = free) instead of 19
// misaligned ds_read_b32 — cuts the measured LDS-pipe occupancy (~19us/step,
// the largest single cost) nearly in half for layer 1.
// CODEGEN RULES (R3-R10): NO unroll pragmas on weight loops (R6/R8 spill
// catastrophes); rolled MAC loops keep the s_load path; float4 staging only.
// ---------------------------------------------------------------------------
template<bool LAST>
__global__ __launch_bounds__(1024, 8)
void nca_step(const float* __restrict__ img,
              const float* __restrict__ W1, const float* __restrict__ b1,
              const float* __restrict__ W2, const float* __restrict__ b2,
              const float* __restrict__ W3, const float* __restrict__ b3,
              const float* __restrict__ state_old, float* __restrict__ state_new,
              int* perc, float* __restrict__ guesses_out,
              float* __restrict__ class_out) {
    __shared__ float s_state[10 * NPIX * CPAD];     // 6400 floats = 25.6 KB
    __shared__ float s_img[NPIX * NPIX];            // 4 KB
    __shared__ float s_h[240 * HSTRIDE];            // 29.8 KB

    const int b   = blockIdx.y;
    const int rg  = blockIdx.x;
    const int i0  = (rg < 2) ? rg * 8 : 16 + (rg - 2) * 7;
    const int nr  = (rg < 2) ? 8 : 7;
    const int tid = threadIdx.x;
    const int qh  = __builtin_amdgcn_readfirstlane(tid >> 8);   // wave-uniform
    const int cell = tid & 255;
    const int qoff = (qh == 0) ? 0 : (qh == 1) ? 8 : (qh == 2) ? 14 : 22;
    const int off3 = 5 * qh;

    {
        const int n4 = (nr + 2) * NPIX * CPAD / 4;   // 1440 or 1600
        const float4* gstate4 =
            (const float4*)(state_old + ((size_t)b * NPIX + i0) * NPIX * CPAD);
        float4* s_state4 = (float4*)s_state;
        for (int t = tid; t < n4; t += 1024) s_state4[t] = gstate4[t];
    }
    if (tid < NPIX * NPIX / 4) {
        ((float4*)s_img)[tid] = ((const float4*)(img + (size_t)b * NPIX * NPIX))[tid];
    }
    __syncthreads();

    const int cells = nr * NNEO;
    const bool active = cell < cells;

    int r = 0, j = 0, i = 0, gcell = 0, px = 0, py = 0;
    if (active) {
        r = cell / NNEO;
        j = cell % NNEO;
        i = i0 + r;
        gcell = (b * NNEO + i) * NNEO + j;
        px = perc[2 * gcell]; py = perc[2 * gcell + 1];
    }

    // ---------------- layer 1: 182 -> 30 (this thread: 8 @ qoff) ----------
    float h1[8];
    {
        const float* __restrict__ bb = b1 + qoff;
#pragma unroll
        for (int q = 0; q < 8; q++) h1[q] = bb[q];
    }
    if (active) {
        for (int pr = 0; pr < 3; pr++) {
            for (int pc = 0; pc < 3; pc++) {
                const int p9 = pr * 3 + pc;
                const float iv = s_img[(px + pr) * NPIX + (py + pc)];
                const float* __restrict__ wp = W1 + (p9 * 20) * 30 + qoff;
                // fv burst: 5 x ds_read_b128 (pixel block is 16B-aligned)
                const int sbase = ((r + pr) * NPIX + (j + pc)) * CPAD;
                float fv[20];
                {
                    const float4* __restrict__ sp =
                        (const float4*)&s_state[sbase];
#pragma unroll
                    for (int v = 0; v < 5; v++)
                        *(float4*)&fv[4 * v] = sp[v];
                }
                // row 0: image feature
#pragma unroll
                for (int q = 0; q < 8; q++) h1[q] += iv * wp[q];
                // rows 1..19: state channels (rolled — keep s_load path)
                for (int ch = 0; ch < CSTATE; ch++) {
                    const float* __restrict__ wr = wp + (ch + 1) * 30;
#pragma unroll
                    for (int q = 0; q < 8; q++) h1[q] += fv[ch] * wr[q];
                }
            }
        }
        const float posx = (float)(px - 16) * (1.0f / 16.0f);
        const float posy = (float)(py - 16) * (1.0f / 16.0f);
        const float* __restrict__ wx = W1 + 180 * 30 + qoff;
        const float* __restrict__ wy = W1 + 181 * 30 + qoff;
#pragma unroll
        for (int q = 0; q < 8; q++) h1[q] += posx * wx[q];
#pragma unroll
        for (int q = 0; q < 8; q++) h1[q] += posy * wy[q];
#pragma unroll
        for (int q = 0; q < 8; q++) h1[q] = fmaxf(h1[q], 0.0f);
#pragma unroll
        for (int q = 0; q < 8; q++) s_h[cell * HSTRIDE + qoff + q] = h1[q];
    }
    __syncthreads();

    // ---------------- layer 2: 30 -> 30 (this thread: 8 @ qoff) -----------
    float h2[8];
    {
        const float* __restrict__ bb = b2 + qoff;
#pragma unroll
        for (int q = 0; q < 8; q++) h2[q] = bb[q];
    }
    if (active) {
        float a1[30];
#pragma unroll
        for (int k = 0; k < 30; k++) a1[k] = s_h[cell * HSTRIDE + k];
        for (int k = 0; k < 30; k++) {
            const float* __restrict__ wr = W2 + k * 30 + qoff;
#pragma unroll
            for (int q = 0; q < 8; q++) h2[q] += a1[k] * wr[q];
        }
#pragma unroll
        for (int q = 0; q < 8; q++) h2[q] = fmaxf(h2[q], 0.0f);
    }
    __syncthreads();   // all a1 reads done before overwrite
    if (active) {
#pragma unroll
        for (int q = 0; q < 8; q++) s_h[cell * HSTRIDE + qoff + q] = h2[q];
    }
    __syncthreads();

    // ---------------- layer 3: 30 -> 21 (this thread: 6 @ off3) -----------
    float o[6];
    {
        const float* __restrict__ bb = b3 + off3;
#pragma unroll
        for (int c = 0; c < 6; c++) o[c] = bb[c];
    }
    if (active) {
        float a2[30];
#pragma unroll
        for (int k = 0; k < 30; k++) a2[k] = s_h[cell * HSTRIDE + k];
        for (int k = 0; k < 30; k++) {
            const float* __restrict__ wr = W3 + k * 21 + off3;
#pragma unroll
            for (int c = 0; c < 6; c++) o[c] += a2[k] * wr[c];
        }

        const int lcenter = ((r + 1) * NPIX + (j + 1)) * CPAD;
        if (!LAST) {
            float* __restrict__ ns =
                state_new + (((size_t)b * NPIX + (i + 1)) * NPIX + (j + 1)) * CPAD;
            // disjoint channel slices: q0 -> ch0-5, q1 -> ch6-10,
            // q2 -> ch11-15, q3 -> ch16-18 + movement (ch19,20 = o[4],o[5])
            if (qh == 0) {
#pragma unroll
                for (int c = 0; c < 6; c++)
                    ns[c] = s_state[lcenter + c] + o[c];
            } else if (qh < 3) {
#pragma unroll
                for (int c = 1; c < 6; c++)
                    ns[off3 + c] = s_state[lcenter + off3 + c] + o[c];
            } else {
#pragma unroll
                for (int c = 1; c < 4; c++)
                    ns[15 + c] = s_state[lcenter + 15 + c] + o[c];
                int dxm = (o[4] > THRESHV) ? 1 : ((o[4] < -THRESHV) ? -1 : 0);
                int dym = (o[5] > THRESHV) ? 1 : ((o[5] < -THRESHV) ? -1 : 0);
                px += dxm; py += dym;
                px = (px < 0) ? 0 : ((px > NNEO - 1) ? NNEO - 1 : px);
                py = (py < 0) ? 0 : ((py > NNEO - 1) ? NNEO - 1 : py);
                perc[2 * gcell + 0] = px;
                perc[2 * gcell + 1] = py;
            }
        } else {
            float* __restrict__ g = guesses_out + (size_t)gcell * OUTD;
            if (qh == 0) {
#pragma unroll
                for (int c = 0; c < 6; c++) g[c] = o[c];
            } else {
#pragma unroll
                for (int c = 1; c < 6; c++) g[off3 + c] = o[c];
            }
            if (qh == 3) {
                float* __restrict__ cs = class_out + (size_t)gcell * 3;
#pragma unroll
                for (int cc = 0; cc < 3; cc++)
                    cs[cc] = s_state[lcenter + 16 + cc] + o[1 + cc];
            }
        }
    }
}

extern "C" void kernel_launch(void* const* d_in, const int* in_sizes, int n_in,
                              void* d_out, int out_size, void* d_ws, size_t ws_size,
                              hipStream_t stream) {
    const float* img = (const float*)d_in[0];
    const float* W1  = (const float*)d_in[1];
    const float* b1  = (const float*)d_in[2];
    const float* W2  = (const float*)d_in[3];
    const float* b2  = (const float*)d_in[4];
    const float* W3  = (const float*)d_in[5];
    const float* b3  = (const float*)d_in[6];

    float* out = (float*)d_out;
    float* class_out   = out;                 // 345,600 floats
    float* guesses_out = out + CLASS_ELEMS;   // 2,419,200 floats

    float* stateA = (float*)d_ws;
    float* stateB = stateA + STATE_ELEMS_PAD;
    int*   perc   = (int*)(stateB + STATE_ELEMS_PAD);

    {
        const int total = B_ * 124 * CPAD;
        nca_init<<<(total + 255) / 256, 256, 0, stream>>>(stateA, stateB);
    }

    const dim3 grid(4, B_);
    // t = 0: standalone kernel, writes stateB, sets perc
    nca_step0<<<grid, 1024, 0, stream>>>(img, W1, b1, W2, b2, W3, b3,
                                         stateB, perc);
    // t = 1..8: mid steps
    for (int t = 1; t < ITERS - 1; t++) {
        const float* so = (t & 1) ? stateB : stateA;
        float*       sn = (t & 1) ? stateA : stateB;
        nca_step<false><<<grid, 1024, 0, stream>>>(
            img, W1, b1, W2, b2, W3, b3, so, sn, perc, guesses_out, class_out);
    }
    // t = 9 (odd): reads stateB, emits outputs only
    nca_step<true><<<grid, 1024, 0, stream>>>(
        img, W1, b1, W2, b2, W3, b3, stateB, stateA, perc, guesses_out, class_out);
}